// Round 1
// baseline (1463.066 us; speedup 1.0000x reference)
//
#include <hip/hip_runtime.h>
#include <stdint.h>

// Problem constants (fixed by setup_inputs): B=8, L=K=2048, D=64
#define BATCH 8
#define NPTS  2048
#define DIM   64
#define VECN  (BATCH*NPTS)   // 16384

typedef __attribute__((ext_vector_type(8))) short bf16x8;
typedef __attribute__((ext_vector_type(4))) float f32x4;

// ---- workspace layout (bytes) ----  total ~5 MB
static constexpr size_t XB_OFF   = 0;                                  // bf16 x  : 2 MB
static constexpr size_t YB_OFF   = (size_t)VECN * DIM * 2;             // bf16 y  : 2 MB
static constexpr size_t NX_OFF   = YB_OFF * 2;                         // f32 ||x||^2
static constexpr size_t NY_OFF   = NX_OFF + (size_t)VECN * 4;
static constexpr size_t LA_OFF   = NY_OFF + (size_t)VECN * 4;
static constexpr size_t LB_OFF   = LA_OFF + (size_t)VECN * 4;
static constexpr size_t POT_OFF  = LB_OFF + (size_t)VECN * 4;          // 8 pot bufs (2 x {pxx,pyy,pxy,pyx})
static constexpr size_t FOUT_OFF = POT_OFF + (size_t)8 * VECN * 4;     // f, g, ge, fe

__device__ inline ushort f2bf(float f) {
  uint32_t u = __float_as_uint(f);
  u += 0x7fffu + ((u >> 16) & 1u);   // RNE
  return (ushort)(u >> 16);
}

// One wave per row: convert to bf16 + exact f32 squared norm.
__global__ void prep_convert(const float* __restrict__ x, const float* __restrict__ y,
                             ushort* __restrict__ xb, ushort* __restrict__ yb,
                             float* __restrict__ nx, float* __restrict__ ny) {
  int wid  = (blockIdx.x * blockDim.x + threadIdx.x) >> 6;
  int lane = threadIdx.x & 63;
  const float* src; ushort* dst; float* nrm; int row;
  if (wid < VECN) { src = x; dst = xb; nrm = nx; row = wid; }
  else            { src = y; dst = yb; nrm = ny; row = wid - VECN; }
  float v = src[(size_t)row * DIM + lane];
  dst[(size_t)row * DIM + lane] = f2bf(v);
  float sq = v * v;
  #pragma unroll
  for (int off = 32; off; off >>= 1) sq += __shfl_xor(sq, off);
  if (lane == 0) nrm[row] = sq;
}

// log-weights + zero all potential buffers
__global__ void prep_vecs(const float* __restrict__ a, const float* __restrict__ b,
                          float* __restrict__ la, float* __restrict__ lb,
                          float* __restrict__ pots) {
  int i = blockIdx.x * blockDim.x + threadIdx.x;
  la[i] = logf(a[i]);
  lb[i] = logf(b[i]);
  #pragma unroll
  for (int j = 0; j < 8; ++j) pots[(size_t)j * VECN + i] = 0.f;
}

// Fused "extrapolation" (flash-LSE) kernel.
//   out[l] = -logsumexp_k( -max(nU[l]+nV[k]-2*U_l.V_k, 0) + potV[k] + logw[k] )
// grid: (NPTS/64, BATCH, 4 jobs); block: 256 (4 waves, each 16 rows)
__global__ __launch_bounds__(256)
void extrap_kernel(const ushort* __restrict__ xb, const ushort* __restrict__ yb,
                   const float* __restrict__ nx, const float* __restrict__ ny,
                   const float* __restrict__ la, const float* __restrict__ lb,
                   const float* __restrict__ pin, float* __restrict__ pout, int avg) {
  const ushort *U, *V; const float *nU, *nV, *potV, *lw, *prevp; float* outp;
  switch (blockIdx.z) {  // pot buf order: 0 pxx, 1 pyy, 2 pxy, 3 pyx
    case 0:  U=xb; V=xb; nU=nx; nV=nx; potV=pin+0*VECN; lw=la; prevp=pin+0*VECN; outp=pout+0*VECN; break; // xx
    case 1:  U=yb; V=yb; nU=ny; nV=ny; potV=pin+1*VECN; lw=lb; prevp=pin+1*VECN; outp=pout+1*VECN; break; // yy
    case 2:  U=xb; V=yb; nU=nx; nV=ny; potV=pin+3*VECN; lw=lb; prevp=pin+2*VECN; outp=pout+2*VECN; break; // xy (uses pyx)
    default: U=yb; V=xb; nU=ny; nV=nx; potV=pin+2*VECN; lw=la; prevp=pin+3*VECN; outp=pout+3*VECN; break; // yx (uses pxy)
  }
  const int batch = blockIdx.y;
  const int lane  = threadIdx.x & 63;
  const int w     = threadIdx.x >> 6;      // wave 0..3
  const int g     = lane >> 4;             // k-chunk group 0..3
  const int c     = lane & 15;             // column-within-tile
  const int rowbase = blockIdx.x * 64 + w * 16;

  const ushort* Ub = U + ((size_t)batch * NPTS + rowbase) * DIM;
  const ushort* Vb = V + (size_t)batch * NPTS * DIM;
  const float* nUb = nU + (size_t)batch * NPTS + rowbase;
  const float* nVb = nV + (size_t)batch * NPTS;
  const float* potb = potV + (size_t)batch * NPTS;
  const float* lwb  = lw  + (size_t)batch * NPTS;

  // A fragments: lane holds U[row=c][k = g*8 .. g*8+7] (and +32 for second mfma)
  bf16x8 a0 = *(const bf16x8*)(Ub + (size_t)c * DIM + g * 8);
  bf16x8 a1 = *(const bf16x8*)(Ub + (size_t)c * DIM + 32 + g * 8);

  float nxr[4];
  #pragma unroll
  for (int r = 0; r < 4; ++r) nxr[r] = nUb[g * 4 + r];   // C/D row = 4*g + r

  float m[4], s[4];
  #pragma unroll
  for (int r = 0; r < 4; ++r) { m[r] = -INFINITY; s[r] = 0.f; }

  #pragma unroll 2
  for (int n0 = 0; n0 < NPTS; n0 += 32) {
    // two 16-col subtiles
    bf16x8 b0a = *(const bf16x8*)(Vb + (size_t)(n0 + c) * DIM + g * 8);
    bf16x8 b0b = *(const bf16x8*)(Vb + (size_t)(n0 + c) * DIM + 32 + g * 8);
    bf16x8 b1a = *(const bf16x8*)(Vb + (size_t)(n0 + 16 + c) * DIM + g * 8);
    bf16x8 b1b = *(const bf16x8*)(Vb + (size_t)(n0 + 16 + c) * DIM + 32 + g * 8);
    float ny0 = nVb[n0 + c],      ny1 = nVb[n0 + 16 + c];
    float w0  = potb[n0 + c] + lwb[n0 + c];
    float w1  = potb[n0 + 16 + c] + lwb[n0 + 16 + c];

    f32x4 acc0 = {0.f, 0.f, 0.f, 0.f}, acc1 = {0.f, 0.f, 0.f, 0.f};
    acc0 = __builtin_amdgcn_mfma_f32_16x16x32_bf16(a0, b0a, acc0, 0, 0, 0);
    acc0 = __builtin_amdgcn_mfma_f32_16x16x32_bf16(a1, b0b, acc0, 0, 0, 0);
    acc1 = __builtin_amdgcn_mfma_f32_16x16x32_bf16(a0, b1a, acc1, 0, 0, 0);
    acc1 = __builtin_amdgcn_mfma_f32_16x16x32_bf16(a1, b1b, acc1, 0, 0, 0);

    #pragma unroll
    for (int r = 0; r < 4; ++r) {
      float d0 = fmaf(-2.f, acc0[r], nxr[r] + ny0); d0 = fmaxf(d0, 0.f);
      float d1 = fmaf(-2.f, acc1[r], nxr[r] + ny1); d1 = fmaxf(d1, 0.f);
      float t0 = w0 - d0;
      float t1 = w1 - d1;
      float mn = fmaxf(fmaxf(m[r], t0), t1);       // v_max3
      s[r] = s[r] * __expf(m[r] - mn) + __expf(t0 - mn) + __expf(t1 - mn);
      m[r] = mn;
    }
  }

  // merge across the 16 lanes of each group (they hold disjoint column subsets)
  #pragma unroll
  for (int r = 0; r < 4; ++r) {
    #pragma unroll
    for (int off = 1; off < 16; off <<= 1) {
      float mo = __shfl_xor(m[r], off);
      float so = __shfl_xor(s[r], off);
      float mn = fmaxf(m[r], mo);
      s[r] = s[r] * __expf(m[r] - mn) + so * __expf(mo - mn);
      m[r] = mn;
    }
  }
  if (c == 0) {
    #pragma unroll
    for (int r = 0; r < 4; ++r) {
      int row = rowbase + g * 4 + r;
      float val = -(m[r] + logf(s[r]));
      if (avg) val = 0.5f * (val + prevp[(size_t)batch * NPTS + row]);
      outp[(size_t)batch * NPTS + row] = val;
    }
  }
}

// res = ( sum (ge-f)*a + sum (fe-g)*b ) / BATCH  -> single scalar
__global__ void reduce_kernel(const float* __restrict__ fouts,
                              const float* __restrict__ a, const float* __restrict__ b,
                              float* __restrict__ out) {
  const float* f  = fouts;
  const float* g  = fouts + (size_t)VECN;
  const float* ge = fouts + (size_t)2 * VECN;
  const float* fe = fouts + (size_t)3 * VECN;
  int tid = threadIdx.x;
  float acc = 0.f;
  for (int i = tid; i < VECN; i += 1024)
    acc += (ge[i] - f[i]) * a[i] + (fe[i] - g[i]) * b[i];
  #pragma unroll
  for (int off = 32; off; off >>= 1) acc += __shfl_xor(acc, off);
  __shared__ float red[16];
  if ((tid & 63) == 0) red[tid >> 6] = acc;
  __syncthreads();
  if (tid < 64) {
    float v = (tid < 16) ? red[tid] : 0.f;
    #pragma unroll
    for (int off = 8; off; off >>= 1) v += __shfl_xor(v, off);
    if (tid == 0) out[0] = v / (float)BATCH;
  }
}

extern "C" void kernel_launch(void* const* d_in, const int* in_sizes, int n_in,
                              void* d_out, int out_size, void* d_ws, size_t ws_size,
                              hipStream_t stream) {
  const float* x = (const float*)d_in[0];
  const float* a = (const float*)d_in[1];
  const float* y = (const float*)d_in[2];
  const float* b = (const float*)d_in[3];
  char* ws = (char*)d_ws;
  ushort* xb = (ushort*)(ws + XB_OFF);
  ushort* yb = (ushort*)(ws + YB_OFF);
  float* nx  = (float*)(ws + NX_OFF);
  float* ny  = (float*)(ws + NY_OFF);
  float* la  = (float*)(ws + LA_OFF);
  float* lb  = (float*)(ws + LB_OFF);
  float* pots  = (float*)(ws + POT_OFF);   // 8 x VECN
  float* fouts = (float*)(ws + FOUT_OFF);  // 4 x VECN

  prep_convert<<<dim3(2 * VECN / 4), 256, 0, stream>>>(x, y, xb, yb, nx, ny);
  prep_vecs<<<dim3(VECN / 256), 256, 0, stream>>>(a, b, la, lb, pots);

  int cur = 0;
  for (int it = 0; it < 10; ++it) {
    extrap_kernel<<<dim3(NPTS / 64, BATCH, 4), 256, 0, stream>>>(
        xb, yb, nx, ny, la, lb,
        pots + (size_t)cur * 4 * VECN, pots + (size_t)(cur ^ 1) * 4 * VECN, 1);
    cur ^= 1;
  }
  // final extrapolation (no averaging) -> f, g, ge, fe
  extrap_kernel<<<dim3(NPTS / 64, BATCH, 4), 256, 0, stream>>>(
      xb, yb, nx, ny, la, lb, pots + (size_t)cur * 4 * VECN, fouts, 0);

  reduce_kernel<<<1, 1024, 0, stream>>>(fouts, a, b, (float*)d_out);
}

// Round 3
// 1453.708 us; speedup vs baseline: 1.0064x; 1.0064x over previous
//
#include <hip/hip_runtime.h>
#include <stdint.h>

// Problem constants (fixed by setup_inputs): B=8, L=K=2048, D=64
#define BATCH 8
#define NPTS  2048
#define DIM   64
#define VECN  (BATCH*NPTS)   // 16384
#define KH    1024           // split-K half width

typedef __attribute__((ext_vector_type(8))) short bf16x8;
typedef __attribute__((ext_vector_type(4))) float f32x4;

#define IL2 1.4426950408889634f
#define LN2 0.6931471805599453f

__device__ inline float fexp2(float x) { return __builtin_amdgcn_exp2f(x); }
__device__ inline float flog2(float x) { return __builtin_amdgcn_logf(x); }

// ---- workspace layout (bytes) ----
static constexpr size_t XB_OFF   = 0;                                   // bf16 x : 2 MB
static constexpr size_t YB_OFF   = (size_t)VECN * DIM * 2;              // bf16 y : 2 MB
static constexpr size_t NX2_OFF  = YB_OFF * 2;                          // ||x||^2 * IL2
static constexpr size_t NY2_OFF  = NX2_OFF + (size_t)VECN * 4;
static constexpr size_t LA2_OFF  = NY2_OFF + (size_t)VECN * 4;          // log2(a)
static constexpr size_t LB2_OFF  = LA2_OFF + (size_t)VECN * 4;          // log2(b)
static constexpr size_t POT_OFF  = LB2_OFF + (size_t)VECN * 4;          // 4 pots
static constexpr size_t WARR_OFF = POT_OFF + (size_t)4 * VECN * 4;      // (pot+lw)*IL2 per job
static constexpr size_t PM_OFF   = WARR_OFF + (size_t)4 * VECN * 4;     // partial max [2][4][VECN]
static constexpr size_t PS_OFF   = PM_OFF + (size_t)8 * VECN * 4;       // partial sum [2][4][VECN]
static constexpr size_t FOUT_OFF = PS_OFF + (size_t)8 * VECN * 4;       // f,g,ge,fe

__device__ inline ushort f2bf(float f) {
  uint32_t u = __float_as_uint(f);
  u += 0x7fffu + ((u >> 16) & 1u);   // RNE
  return (ushort)(u >> 16);
}

// One wave per row: convert to bf16 + exact f32 squared norm (scaled by IL2).
__global__ void prep_convert(const float* __restrict__ x, const float* __restrict__ y,
                             ushort* __restrict__ xb, ushort* __restrict__ yb,
                             float* __restrict__ nx2, float* __restrict__ ny2) {
  int wid  = (blockIdx.x * blockDim.x + threadIdx.x) >> 6;
  int lane = threadIdx.x & 63;
  const float* src; ushort* dst; float* nrm; int row;
  if (wid < VECN) { src = x; dst = xb; nrm = nx2; row = wid; }
  else            { src = y; dst = yb; nrm = ny2; row = wid - VECN; }
  float v = src[(size_t)row * DIM + lane];
  dst[(size_t)row * DIM + lane] = f2bf(v);
  float sq = v * v;
  #pragma unroll
  for (int off = 32; off; off >>= 1) sq += __shfl_xor(sq, off);
  if (lane == 0) nrm[row] = sq * IL2;
}

// log2-weights + init warr (pot=0 -> warr = lw2) + zero pots
__global__ void prep_vecs(const float* __restrict__ a, const float* __restrict__ b,
                          float* __restrict__ la2, float* __restrict__ lb2,
                          float* __restrict__ pot, float* __restrict__ warr) {
  int i = blockIdx.x * blockDim.x + threadIdx.x;
  float l2a = log2f(a[i]);
  float l2b = log2f(b[i]);
  la2[i] = l2a;
  lb2[i] = l2b;
  warr[i] = l2a;                        // job 0: pxx + la
  warr[(size_t)VECN + i] = l2b;         // job 1: pyy + lb
  warr[(size_t)2 * VECN + i] = l2b;     // job 2: pyx + lb
  warr[(size_t)3 * VECN + i] = l2a;     // job 3: pxy + la
  #pragma unroll
  for (int j = 0; j < 4; ++j) pot[(size_t)j * VECN + i] = 0.f;
}

// Fused flash-LSE partial kernel (split-K, log2 domain).
// grid: ((NPTS/64)*2, BATCH, 4 jobs); block 256 (4 waves, 16 rows each)
__global__ __launch_bounds__(256, 8)
void extrap_kernel(const ushort* __restrict__ xb, const ushort* __restrict__ yb,
                   const float* __restrict__ nx2, const float* __restrict__ ny2,
                   const float* __restrict__ warr,
                   float* __restrict__ pm, float* __restrict__ ps) {
  const int rb    = blockIdx.x >> 1;
  const int half  = blockIdx.x & 1;
  const int batch = blockIdx.y;
  const int z     = blockIdx.z;
  const ushort *U, *V; const float *nU2, *nV2;
  switch (z) {
    case 0:  U = xb; V = xb; nU2 = nx2; nV2 = nx2; break; // xx
    case 1:  U = yb; V = yb; nU2 = ny2; nV2 = ny2; break; // yy
    case 2:  U = xb; V = yb; nU2 = nx2; nV2 = ny2; break; // xy
    default: U = yb; V = xb; nU2 = ny2; nV2 = nx2; break; // yx
  }
  const int lane = threadIdx.x & 63;
  const int w    = threadIdx.x >> 6;
  const int g    = lane >> 4;
  const int c    = lane & 15;
  const int rowbase = rb * 64 + w * 16;

  const ushort* Ub  = U + ((size_t)batch * NPTS + rowbase) * DIM;
  const ushort* Vb  = V + ((size_t)batch * NPTS + half * KH) * DIM;
  const float*  nVb = nV2 + (size_t)batch * NPTS + half * KH;
  const float*  wb  = warr + (size_t)z * VECN + (size_t)batch * NPTS + half * KH;

  bf16x8 a0 = *(const bf16x8*)(Ub + (size_t)c * DIM + g * 8);
  bf16x8 a1 = *(const bf16x8*)(Ub + (size_t)c * DIM + 32 + g * 8);

  float nxr2[4];
  #pragma unroll
  for (int r = 0; r < 4; ++r) nxr2[r] = nU2[(size_t)batch * NPTS + rowbase + g * 4 + r];

  float m[4], s[4];
  #pragma unroll
  for (int r = 0; r < 4; ++r) { m[r] = -INFINITY; s[r] = 0.f; }

  #pragma unroll 2
  for (int n0 = 0; n0 < KH; n0 += 32) {
    bf16x8 b0a = *(const bf16x8*)(Vb + (size_t)(n0 + c) * DIM + g * 8);
    bf16x8 b0b = *(const bf16x8*)(Vb + (size_t)(n0 + c) * DIM + 32 + g * 8);
    bf16x8 b1a = *(const bf16x8*)(Vb + (size_t)(n0 + 16 + c) * DIM + g * 8);
    bf16x8 b1b = *(const bf16x8*)(Vb + (size_t)(n0 + 16 + c) * DIM + 32 + g * 8);
    float nv0 = nVb[n0 + c],  nv1 = nVb[n0 + 16 + c];
    float w0  = wb[n0 + c],   w1  = wb[n0 + 16 + c];

    f32x4 acc0 = {0.f, 0.f, 0.f, 0.f}, acc1 = {0.f, 0.f, 0.f, 0.f};
    acc0 = __builtin_amdgcn_mfma_f32_16x16x32_bf16(a0, b0a, acc0, 0, 0, 0);
    acc0 = __builtin_amdgcn_mfma_f32_16x16x32_bf16(a1, b0b, acc0, 0, 0, 0);
    acc1 = __builtin_amdgcn_mfma_f32_16x16x32_bf16(a0, b1a, acc1, 0, 0, 0);
    acc1 = __builtin_amdgcn_mfma_f32_16x16x32_bf16(a1, b1b, acc1, 0, 0, 0);

    #pragma unroll
    for (int r = 0; r < 4; ++r) {
      float d0 = fmaxf(fmaf(-2.f * IL2, acc0[r], nxr2[r] + nv0), 0.f);
      float d1 = fmaxf(fmaf(-2.f * IL2, acc1[r], nxr2[r] + nv1), 0.f);
      float t0 = w0 - d0;
      float t1 = w1 - d1;
      float mn = fmaxf(m[r], fmaxf(t0, t1));       // v_max3
      s[r] = fmaf(s[r], fexp2(m[r] - mn), fexp2(t0 - mn) + fexp2(t1 - mn));
      m[r] = mn;
    }
  }

  // merge across the 16 lanes of each group (disjoint column subsets)
  #pragma unroll
  for (int r = 0; r < 4; ++r) {
    #pragma unroll
    for (int off = 1; off < 16; off <<= 1) {
      float mo = __shfl_xor(m[r], off);
      float so = __shfl_xor(s[r], off);
      float mn = fmaxf(m[r], mo);
      s[r] = fmaf(s[r], fexp2(m[r] - mn), so * fexp2(mo - mn));
      m[r] = mn;
    }
  }
  if (c == 0) {
    #pragma unroll
    for (int r = 0; r < 4; ++r) {
      size_t idx = (size_t)(half * 4 + z) * VECN + (size_t)batch * NPTS + rowbase + g * 4 + r;
      pm[idx] = m[r];
      ps[idx] = s[r];
    }
  }
}

// Combine split-K partials, apply 0.5-averaging, produce next-iter warr.
// grid: 4*VECN/256 blocks
__global__ void merge_kernel(const float* __restrict__ pm, const float* __restrict__ ps,
                             float* __restrict__ pot,
                             const float* __restrict__ la2, const float* __restrict__ lb2,
                             float* __restrict__ warr, float* __restrict__ fouts, int avg) {
  int i = blockIdx.x * blockDim.x + threadIdx.x;       // 0 .. 4*VECN
  int z = i >> 14;                                     // VECN = 16384
  int iin = i & (VECN - 1);
  float m0 = pm[i], m1 = pm[(size_t)4 * VECN + i];
  float s0 = ps[i], s1 = ps[(size_t)4 * VECN + i];
  float mn = fmaxf(m0, m1);
  float s  = fmaf(s0, fexp2(m0 - mn), s1 * fexp2(m1 - mn));
  float val = -LN2 * (mn + flog2(s));
  if (avg) {
    val = 0.5f * (val + pot[i]);
    pot[i] = val;
    int cjob = z ^ (z >> 1);                           // 0,1 self; 2<->3
    const float* lw2 = (z & 1) ? lb2 : la2;
    warr[(size_t)cjob * VECN + iin] = fmaf(val, IL2, lw2[iin]);
  } else {
    fouts[i] = val;
  }
}

// res = ( sum (ge-f)*a + sum (fe-g)*b ) / BATCH  -> single scalar
__global__ void reduce_kernel(const float* __restrict__ fouts,
                              const float* __restrict__ a, const float* __restrict__ b,
                              float* __restrict__ out) {
  const float* f  = fouts;
  const float* g  = fouts + (size_t)VECN;
  const float* ge = fouts + (size_t)2 * VECN;
  const float* fe = fouts + (size_t)3 * VECN;
  int tid = threadIdx.x;
  float acc = 0.f;
  for (int i = tid; i < VECN; i += 1024)
    acc += (ge[i] - f[i]) * a[i] + (fe[i] - g[i]) * b[i];
  #pragma unroll
  for (int off = 32; off; off >>= 1) acc += __shfl_xor(acc, off);
  __shared__ float red[16];
  if ((tid & 63) == 0) red[tid >> 6] = acc;
  __syncthreads();
  if (tid < 64) {
    float v = (tid < 16) ? red[tid] : 0.f;
    #pragma unroll
    for (int off = 8; off; off >>= 1) v += __shfl_xor(v, off);
    if (tid == 0) out[0] = v / (float)BATCH;
  }
}

extern "C" void kernel_launch(void* const* d_in, const int* in_sizes, int n_in,
                              void* d_out, int out_size, void* d_ws, size_t ws_size,
                              hipStream_t stream) {
  const float* x = (const float*)d_in[0];
  const float* a = (const float*)d_in[1];
  const float* y = (const float*)d_in[2];
  const float* b = (const float*)d_in[3];
  char* ws = (char*)d_ws;
  ushort* xb  = (ushort*)(ws + XB_OFF);
  ushort* yb  = (ushort*)(ws + YB_OFF);
  float* nx2  = (float*)(ws + NX2_OFF);
  float* ny2  = (float*)(ws + NY2_OFF);
  float* la2  = (float*)(ws + LA2_OFF);
  float* lb2  = (float*)(ws + LB2_OFF);
  float* pot  = (float*)(ws + POT_OFF);
  float* warr = (float*)(ws + WARR_OFF);
  float* pm   = (float*)(ws + PM_OFF);
  float* ps   = (float*)(ws + PS_OFF);
  float* fouts= (float*)(ws + FOUT_OFF);

  prep_convert<<<dim3(2 * VECN / 4), 256, 0, stream>>>(x, y, xb, yb, nx2, ny2);
  prep_vecs<<<dim3(VECN / 256), 256, 0, stream>>>(a, b, la2, lb2, pot, warr);

  for (int it = 0; it < 10; ++it) {
    extrap_kernel<<<dim3((NPTS / 64) * 2, BATCH, 4), 256, 0, stream>>>(
        xb, yb, nx2, ny2, warr, pm, ps);
    merge_kernel<<<dim3(4 * VECN / 256), 256, 0, stream>>>(
        pm, ps, pot, la2, lb2, warr, fouts, 1);
  }
  // final extrapolation (no averaging) -> f, g, ge, fe
  extrap_kernel<<<dim3((NPTS / 64) * 2, BATCH, 4), 256, 0, stream>>>(
      xb, yb, nx2, ny2, warr, pm, ps);
  merge_kernel<<<dim3(4 * VECN / 256), 256, 0, stream>>>(
      pm, ps, pot, la2, lb2, warr, fouts, 0);

  reduce_kernel<<<1, 1024, 0, stream>>>(fouts, a, b, (float*)d_out);
}

// Round 4
// 627.483 us; speedup vs baseline: 2.3316x; 2.3167x over previous
//
#include <hip/hip_runtime.h>
#include <stdint.h>

// Problem constants (fixed by setup_inputs): B=8, L=K=2048, D=64
#define BATCH 8
#define NPTS  2048
#define DIM   64
#define VECN  (BATCH*NPTS)   // 16384
#define KH    1024           // split-K half width
#define CHUNK 64             // columns staged per LDS buffer
#define NCHUNK (KH/CHUNK)    // 16

typedef __attribute__((ext_vector_type(8))) short bf16x8;
typedef __attribute__((ext_vector_type(4))) float f32x4;

#define IL2 1.4426950408889634f
#define LN2 0.6931471805599453f

__device__ inline float fexp2(float x) { return __builtin_amdgcn_exp2f(x); }
__device__ inline float flog2(float x) { return __builtin_amdgcn_logf(x); }

// async global->LDS staging (HW: lds dest = uniform base + lane*size; global src per-lane)
__device__ inline void gload_lds16(const void* g, void* l) {
  __builtin_amdgcn_global_load_lds(
      (const __attribute__((address_space(1))) uint32_t*)g,
      (__attribute__((address_space(3))) uint32_t*)l, 16, 0, 0);
}
__device__ inline void gload_lds4(const void* g, void* l) {
  __builtin_amdgcn_global_load_lds(
      (const __attribute__((address_space(1))) uint32_t*)g,
      (__attribute__((address_space(3))) uint32_t*)l, 4, 0, 0);
}

// ---- workspace layout (bytes) ----
static constexpr size_t XB_OFF   = 0;                                   // bf16 x : 2 MB
static constexpr size_t YB_OFF   = (size_t)VECN * DIM * 2;              // bf16 y : 2 MB
static constexpr size_t NX2_OFF  = YB_OFF * 2;                          // ||x||^2 * IL2
static constexpr size_t NY2_OFF  = NX2_OFF + (size_t)VECN * 4;
static constexpr size_t LA2_OFF  = NY2_OFF + (size_t)VECN * 4;          // log2(a)
static constexpr size_t LB2_OFF  = LA2_OFF + (size_t)VECN * 4;          // log2(b)
static constexpr size_t POT_OFF  = LB2_OFF + (size_t)VECN * 4;          // 4 pots
static constexpr size_t NW_OFF   = POT_OFF + (size_t)4 * VECN * 4;      // float2 (nv2, pot+lw)*... per job
static constexpr size_t PM_OFF   = NW_OFF + (size_t)4 * VECN * 8;       // partial max [2][4][VECN]
static constexpr size_t PS_OFF   = PM_OFF + (size_t)8 * VECN * 4;       // partial sum [2][4][VECN]
static constexpr size_t FOUT_OFF = PS_OFF + (size_t)8 * VECN * 4;       // f,g,ge,fe

__device__ inline ushort f2bf(float f) {
  uint32_t u = __float_as_uint(f);
  u += 0x7fffu + ((u >> 16) & 1u);   // RNE
  return (ushort)(u >> 16);
}

// One wave per row: convert to bf16 + exact f32 squared norm (scaled by IL2).
__global__ void prep_convert(const float* __restrict__ x, const float* __restrict__ y,
                             ushort* __restrict__ xb, ushort* __restrict__ yb,
                             float* __restrict__ nx2, float* __restrict__ ny2) {
  int wid  = (blockIdx.x * blockDim.x + threadIdx.x) >> 6;
  int lane = threadIdx.x & 63;
  const float* src; ushort* dst; float* nrm; int row;
  if (wid < VECN) { src = x; dst = xb; nrm = nx2; row = wid; }
  else            { src = y; dst = yb; nrm = ny2; row = wid - VECN; }
  float v = src[(size_t)row * DIM + lane];
  dst[(size_t)row * DIM + lane] = f2bf(v);
  float sq = v * v;
  #pragma unroll
  for (int off = 32; off; off >>= 1) sq += __shfl_xor(sq, off);
  if (lane == 0) nrm[row] = sq * IL2;
}

// log2-weights, zero pots, init nw[z] = {V-side norm, V-side log2 weight}
__global__ void prep_vecs(const float* __restrict__ a, const float* __restrict__ b,
                          const float* __restrict__ nx2, const float* __restrict__ ny2,
                          float* __restrict__ la2, float* __restrict__ lb2,
                          float* __restrict__ pot, float2* __restrict__ nw) {
  int i = blockIdx.x * blockDim.x + threadIdx.x;
  float l2a = log2f(a[i]);
  float l2b = log2f(b[i]);
  la2[i] = l2a;
  lb2[i] = l2b;
  float nxv = nx2[i], nyv = ny2[i];
  nw[i]                     = make_float2(nxv, l2a);  // z0 xx: V=x
  nw[(size_t)VECN + i]      = make_float2(nyv, l2b);  // z1 yy: V=y
  nw[(size_t)2 * VECN + i]  = make_float2(nyv, l2b);  // z2 xy: V=y (uses pyx+lb)
  nw[(size_t)3 * VECN + i]  = make_float2(nxv, l2a);  // z3 yx: V=x (uses pxy+la)
  #pragma unroll
  for (int j = 0; j < 4; ++j) pot[(size_t)j * VECN + i] = 0.f;
}

// Fused flash-LSE partial kernel: split-K, log2 domain, LDS-staged V (XOR-swizzled).
// grid: ((NPTS/64)*2, BATCH, 4 jobs); block 256 (4 waves, 16 rows each)
__global__ __launch_bounds__(256, 8)
void extrap_kernel(const ushort* __restrict__ xb, const ushort* __restrict__ yb,
                   const float* __restrict__ nx2, const float* __restrict__ ny2,
                   const float2* __restrict__ nw,
                   float* __restrict__ pm, float* __restrict__ ps) {
  __shared__ char vlds[2][CHUNK * 128];   // 2 x 8 KB, swizzled content
  __shared__ char nwlds[2][CHUNK * 8];    // 2 x 512 B, linear float2

  const int rb    = blockIdx.x >> 1;
  const int half  = blockIdx.x & 1;
  const int batch = blockIdx.y;
  const int z     = blockIdx.z;
  const ushort *U, *V; const float *nU2;
  switch (z) {
    case 0:  U = xb; V = xb; nU2 = nx2; break; // xx
    case 1:  U = yb; V = yb; nU2 = ny2; break; // yy
    case 2:  U = xb; V = yb; nU2 = nx2; break; // xy
    default: U = yb; V = xb; nU2 = ny2; break; // yx
  }
  const int lane = threadIdx.x & 63;
  const int w    = threadIdx.x >> 6;
  const int g    = lane >> 4;
  const int c    = lane & 15;
  const int rowbase = rb * 64 + w * 16;

  const ushort* Ub  = U + ((size_t)batch * NPTS + rowbase) * DIM;
  const char*   Vch = (const char*)(V + ((size_t)batch * NPTS + half * KH) * DIM); // 128B rows
  const char*   nwch = (const char*)(nw + (size_t)z * VECN + (size_t)batch * NPTS + half * KH);

  // A fragments: lane holds U[row=c][k = g*8 .. +8) (and +32 for second mfma)
  bf16x8 a0 = *(const bf16x8*)(Ub + (size_t)c * DIM + g * 8);
  bf16x8 a1 = *(const bf16x8*)(Ub + (size_t)c * DIM + 32 + g * 8);

  float nxr2[4];
  #pragma unroll
  for (int r = 0; r < 4; ++r) nxr2[r] = nU2[(size_t)batch * NPTS + rowbase + g * 4 + r];

  // per-lane pre-swizzled staging offset: row r=lane>>3, byte o=(lane&7)*16;
  // source fetches V[r][o ^ ((r&7)<<4)] so that swizzled read returns V[r][q] at q^xr.
  const size_t lane_voff = ((size_t)(lane >> 3)) * 128
                         + (size_t)((((lane & 7) ^ (lane >> 3)) << 4));

  float m[4], s[4];
  #pragma unroll
  for (int r = 0; r < 4; ++r) { m[r] = -INFINITY; s[r] = 0.f; }

  auto stage = [&](int p, int ck) {
    const char* gbase = Vch + (size_t)ck * CHUNK * 128;
    #pragma unroll
    for (int i = 0; i < 2; ++i) {
      int j = w * 2 + i;                                  // 1 KB slab = 8 rows
      gload_lds16(gbase + (size_t)j * 1024 + lane_voff, &vlds[p][j * 1024]);
    }
    if (w == 0) {
      const char* gn = nwch + (size_t)ck * CHUNK * 8;
      gload_lds4(gn + lane * 4,       &nwlds[p][0]);
      gload_lds4(gn + 256 + lane * 4, &nwlds[p][256]);
    }
  };

  auto compute = [&](int p) {
    #pragma unroll
    for (int t = 0; t < 2; ++t) {
      const int rr0 = t * 32 + c;
      const int rr1 = rr0 + 16;
      const int x0 = (rr0 & 7) << 4;           // rr1&7 == rr0&7
      const char* pv0 = &vlds[p][rr0 * 128];
      const char* pv1 = &vlds[p][rr1 * 128];
      bf16x8 b0a = *(const bf16x8*)(pv0 + ((g * 16) ^ x0));
      bf16x8 b0b = *(const bf16x8*)(pv0 + ((64 + g * 16) ^ x0));
      bf16x8 b1a = *(const bf16x8*)(pv1 + ((g * 16) ^ x0));
      bf16x8 b1b = *(const bf16x8*)(pv1 + ((64 + g * 16) ^ x0));
      float2 nw0 = *(const float2*)&nwlds[p][rr0 * 8];
      float2 nw1 = *(const float2*)&nwlds[p][rr1 * 8];

      f32x4 acc0 = {0.f, 0.f, 0.f, 0.f}, acc1 = {0.f, 0.f, 0.f, 0.f};
      acc0 = __builtin_amdgcn_mfma_f32_16x16x32_bf16(a0, b0a, acc0, 0, 0, 0);
      acc0 = __builtin_amdgcn_mfma_f32_16x16x32_bf16(a1, b0b, acc0, 0, 0, 0);
      acc1 = __builtin_amdgcn_mfma_f32_16x16x32_bf16(a0, b1a, acc1, 0, 0, 0);
      acc1 = __builtin_amdgcn_mfma_f32_16x16x32_bf16(a1, b1b, acc1, 0, 0, 0);

      #pragma unroll
      for (int r = 0; r < 4; ++r) {
        float d0 = fmaxf(fmaf(-2.f * IL2, acc0[r], nxr2[r] + nw0.x), 0.f);
        float d1 = fmaxf(fmaf(-2.f * IL2, acc1[r], nxr2[r] + nw1.x), 0.f);
        float t0 = nw0.y - d0;
        float t1 = nw1.y - d1;
        float mn = fmaxf(m[r], fmaxf(t0, t1));       // v_max3
        s[r] = fmaf(s[r], fexp2(m[r] - mn), fexp2(t0 - mn) + fexp2(t1 - mn));
        m[r] = mn;
      }
    }
  };

  stage(0, 0);
  __syncthreads();
  int p = 0;
  for (int ck = 0; ck < NCHUNK; ++ck) {
    if (ck < NCHUNK - 1) stage(p ^ 1, ck + 1);   // prefetch in flight during compute
    compute(p);
    __syncthreads();                             // drains vmcnt + lgkmcnt, all waves
    p ^= 1;
  }

  // merge across the 16 lanes of each group (disjoint column subsets)
  #pragma unroll
  for (int r = 0; r < 4; ++r) {
    #pragma unroll
    for (int off = 1; off < 16; off <<= 1) {
      float mo = __shfl_xor(m[r], off);
      float so = __shfl_xor(s[r], off);
      float mn = fmaxf(m[r], mo);
      s[r] = fmaf(s[r], fexp2(m[r] - mn), so * fexp2(mo - mn));
      m[r] = mn;
    }
  }
  if (c == 0) {
    #pragma unroll
    for (int r = 0; r < 4; ++r) {
      size_t idx = (size_t)(half * 4 + z) * VECN + (size_t)batch * NPTS + rowbase + g * 4 + r;
      pm[idx] = m[r];
      ps[idx] = s[r];
    }
  }
}

// Combine split-K partials, apply 0.5-averaging, update consumer nw.y for next iter.
__global__ void merge_kernel(const float* __restrict__ pm, const float* __restrict__ ps,
                             float* __restrict__ pot,
                             const float* __restrict__ la2, const float* __restrict__ lb2,
                             float2* __restrict__ nw, float* __restrict__ fouts, int avg) {
  int i = blockIdx.x * blockDim.x + threadIdx.x;       // 0 .. 4*VECN
  int z = i >> 14;                                     // VECN = 16384
  int iin = i & (VECN - 1);
  float m0 = pm[i], m1 = pm[(size_t)4 * VECN + i];
  float s0 = ps[i], s1 = ps[(size_t)4 * VECN + i];
  float mn = fmaxf(m0, m1);
  float s  = fmaf(s0, fexp2(m0 - mn), s1 * fexp2(m1 - mn));
  float val = -LN2 * (mn + flog2(s));
  if (avg) {
    val = 0.5f * (val + pot[i]);
    pot[i] = val;
    int cjob = z ^ (z >> 1);                           // 0,1 self; 2<->3
    const float* lw2 = (z & 1) ? lb2 : la2;
    nw[(size_t)cjob * VECN + iin].y = fmaf(val, IL2, lw2[iin]);
  } else {
    fouts[i] = val;
  }
}

// res = ( sum (ge-f)*a + sum (fe-g)*b ) / BATCH  -> single scalar
__global__ void reduce_kernel(const float* __restrict__ fouts,
                              const float* __restrict__ a, const float* __restrict__ b,
                              float* __restrict__ out) {
  const float* f  = fouts;
  const float* g  = fouts + (size_t)VECN;
  const float* ge = fouts + (size_t)2 * VECN;
  const float* fe = fouts + (size_t)3 * VECN;
  int tid = threadIdx.x;
  float acc = 0.f;
  for (int i = tid; i < VECN; i += 1024)
    acc += (ge[i] - f[i]) * a[i] + (fe[i] - g[i]) * b[i];
  #pragma unroll
  for (int off = 32; off; off >>= 1) acc += __shfl_xor(acc, off);
  __shared__ float red[16];
  if ((tid & 63) == 0) red[tid >> 6] = acc;
  __syncthreads();
  if (tid < 64) {
    float v = (tid < 16) ? red[tid] : 0.f;
    #pragma unroll
    for (int off = 8; off; off >>= 1) v += __shfl_xor(v, off);
    if (tid == 0) out[0] = v / (float)BATCH;
  }
}

extern "C" void kernel_launch(void* const* d_in, const int* in_sizes, int n_in,
                              void* d_out, int out_size, void* d_ws, size_t ws_size,
                              hipStream_t stream) {
  const float* x = (const float*)d_in[0];
  const float* a = (const float*)d_in[1];
  const float* y = (const float*)d_in[2];
  const float* b = (const float*)d_in[3];
  char* ws = (char*)d_ws;
  ushort* xb  = (ushort*)(ws + XB_OFF);
  ushort* yb  = (ushort*)(ws + YB_OFF);
  float* nx2  = (float*)(ws + NX2_OFF);
  float* ny2  = (float*)(ws + NY2_OFF);
  float* la2  = (float*)(ws + LA2_OFF);
  float* lb2  = (float*)(ws + LB2_OFF);
  float* pot  = (float*)(ws + POT_OFF);
  float2* nw  = (float2*)(ws + NW_OFF);
  float* pm   = (float*)(ws + PM_OFF);
  float* ps   = (float*)(ws + PS_OFF);
  float* fouts= (float*)(ws + FOUT_OFF);

  prep_convert<<<dim3(2 * VECN / 4), 256, 0, stream>>>(x, y, xb, yb, nx2, ny2);
  prep_vecs<<<dim3(VECN / 256), 256, 0, stream>>>(a, b, nx2, ny2, la2, lb2, pot, nw);

  for (int it = 0; it < 10; ++it) {
    extrap_kernel<<<dim3((NPTS / 64) * 2, BATCH, 4), 256, 0, stream>>>(
        xb, yb, nx2, ny2, nw, pm, ps);
    merge_kernel<<<dim3(4 * VECN / 256), 256, 0, stream>>>(
        pm, ps, pot, la2, lb2, nw, fouts, 1);
  }
  // final extrapolation (no averaging) -> f, g, ge, fe
  extrap_kernel<<<dim3((NPTS / 64) * 2, BATCH, 4), 256, 0, stream>>>(
      xb, yb, nx2, ny2, nw, pm, ps);
  merge_kernel<<<dim3(4 * VECN / 256), 256, 0, stream>>>(
      pm, ps, pot, la2, lb2, nw, fouts, 0);

  reduce_kernel<<<1, 1024, 0, stream>>>(fouts, a, b, (float*)d_out);
}